// Round 8
// baseline (264.143 us; speedup 1.0000x reference)
//
#include <hip/hip_runtime.h>
#include <math.h>

// Outputs are a pure function of obs's class (NC=1000); heads (am/sd/cr)
// are a pure function of the VQ CODE (VQN=512). Structure as R8:
//   compute: blocks [0,nTB) trunk+VQ (2 classes, shared f4 loads);
//            blocks [nTB,+nHB) heads per code (2 codes/block).
//   scatter: out[b] = tables[idx_t[obs[b]]].
//
// R11: R9 (batched loads) and R10 (sched_barrier pinning) were both null
// => compute is NOT VMEM-schedule-bound. Remaining constraint: VGPR ~176
// capped co-residency at 2 blocks/CU (R5: Occupancy 11%), so per-block
// phase latency never overlapped across blocks. Fix: lean streaming loops
// (R8 arithmetic, verbatim chain orders => absmax 0) + __launch_bounds__
// (256, 4) to cap VGPR at 128 -> 4 blocks/CU. LDS ~30 KB permits 5.

typedef float f4 __attribute__((ext_vector_type(4)));
typedef float f2 __attribute__((ext_vector_type(2)));

__device__ __forceinline__ float sigmoidf_(float x){ return 1.0f/(1.0f + expf(-x)); }

__global__ __launch_bounds__(256, 4) void compute_kernel(
    const float* __restrict__ embed,
    const float* __restrict__ W1, const float* __restrict__ b1,
    const float* __restrict__ W2, const float* __restrict__ b2,
    const float* __restrict__ W3, const float* __restrict__ b3,
    const float* __restrict__ Wp, const float* __restrict__ bp,
    const float* __restrict__ cb,
    const float* __restrict__ Wa, const float* __restrict__ ba,
    const float* __restrict__ Ws, const float* __restrict__ bs,
    const float* __restrict__ Wc1, const float* __restrict__ bc1,
    const float* __restrict__ Wc2, const float* __restrict__ bc2,
    const float* __restrict__ Wc3, const float* __restrict__ bc3,
    const float* __restrict__ Wc4, const float* __restrict__ bc4,
    float* __restrict__ am_c, float* __restrict__ sd_c,
    float* __restrict__ cr_c, int* __restrict__ idx_t, float* __restrict__ e_t,
    float* __restrict__ loss_slot, int VQN, int NC, int nTB)
{
    const int bid = blockIdx.x;
    const int t   = threadIdx.x;     // 0..255
    if (bid == 0 && t == 0) *loss_slot = 0.0f;   // d_out is poisoned each call

    // trunk-branch LDS
    __shared__ double U[2][128], V[2][128];     // layer ping-pong (class A/B)
    __shared__ double part[2][8][128];          // fp64 chain partials
    __shared__ double zp2[2][64];
    __shared__ float  qv2[2][64];
    __shared__ double rda[2][4];
    __shared__ int    ria[2][4];
    __shared__ int    widx2[2];
    // head-branch LDS
    __shared__ float  qvh[2][64];
    __shared__ float  fpart[2][4][128];
    __shared__ float  gpart[2][2][128];
    __shared__ float  h1s[2][128], h2s[2][128], h3s[2][32];

    if (bid < nTB) {
        // ================= trunk + VQ for classes c0, c1 =================
        const int c0  = bid * 2;
        const int c1  = (c0 + 1 < NC) ? c0 + 1 : NC - 1;   // clamp (dup-safe)
        const int cls = t >> 7;          // this thread's class for combines
        const int r   = t & 127;
        const int q4  = (t & 31) << 2;   // output quad (shared-load phases)
        const int h   = t >> 5;          // K-chain 0..7 (i ≡ h mod 8)

        if (t < 128) U[0][t] = (double)embed[(size_t)c0 * 128 + t];
        else         U[1][r] = (double)embed[(size_t)c1 * 128 + r];
        __syncthreads();

        // trunk layer: thread (h,q4) computes chain h of outputs q4..q4+3
        // for BOTH classes from one f4 weight load. Chain 0 carries bias.
        // Chain order verbatim R8.
#define TRUNK2(Wm, bv, IN, OUT)                                               \
        {                                                                     \
            double aA0 = (h == 0) ? (double)bv[q4+0] : 0.0;                   \
            double aA1 = (h == 0) ? (double)bv[q4+1] : 0.0;                   \
            double aA2 = (h == 0) ? (double)bv[q4+2] : 0.0;                   \
            double aA3 = (h == 0) ? (double)bv[q4+3] : 0.0;                   \
            double aB0 = aA0, aB1 = aA1, aB2 = aA2, aB3 = aA3;                \
            _Pragma("unroll")                                                 \
            for (int s = 0; s < 16; ++s) {                                    \
                int i = h + (s << 3);                                         \
                f4 w = *(const f4*)(Wm + (size_t)i * 128 + q4);               \
                double w0 = (double)w.x, w1 = (double)w.y;                    \
                double w2 = (double)w.z, w3 = (double)w.w;                    \
                double xA = IN[0][i], xB = IN[1][i];                          \
                aA0 = fma(xA, w0, aA0);  aB0 = fma(xB, w0, aB0);              \
                aA1 = fma(xA, w1, aA1);  aB1 = fma(xB, w1, aB1);              \
                aA2 = fma(xA, w2, aA2);  aB2 = fma(xB, w2, aB2);              \
                aA3 = fma(xA, w3, aA3);  aB3 = fma(xB, w3, aB3);              \
            }                                                                 \
            part[0][h][q4+0] = aA0; part[0][h][q4+1] = aA1;                   \
            part[0][h][q4+2] = aA2; part[0][h][q4+3] = aA3;                   \
            part[1][h][q4+0] = aB0; part[1][h][q4+1] = aB1;                   \
            part[1][h][q4+2] = aB2; part[1][h][q4+3] = aB3;                   \
        }                                                                     \
        __syncthreads();                                                      \
        {                                                                     \
            double acc = ((part[cls][0][r] + part[cls][1][r])                 \
                        + (part[cls][2][r] + part[cls][3][r]))                \
                       + ((part[cls][4][r] + part[cls][5][r])                 \
                        + (part[cls][6][r] + part[cls][7][r]));               \
            OUT[cls][r] = acc > 0.0 ? acc : 0.0;                              \
        }                                                                     \
        __syncthreads();

        TRUNK2(W1, b1, U, V)
        TRUNK2(W2, b2, V, U)
        TRUNK2(W3, b3, U, V)
#undef TRUNK2

        // zp = z3 @ Wp + bp (64 outs/class): 8 chains x 16 quads
        {
            const int q4p = (r & 15) << 2;
            const int hp  = r >> 4;          // 0..7
            double a0 = (hp == 0) ? (double)bp[q4p+0] : 0.0;
            double a1 = (hp == 0) ? (double)bp[q4p+1] : 0.0;
            double a2 = (hp == 0) ? (double)bp[q4p+2] : 0.0;
            double a3 = (hp == 0) ? (double)bp[q4p+3] : 0.0;
            #pragma unroll
            for (int s = 0; s < 16; ++s) {
                int i = hp + (s << 3);
                f4 w = *(const f4*)(Wp + (size_t)i * 64 + q4p);
                double x = V[cls][i];
                a0 = fma(x, (double)w.x, a0);
                a1 = fma(x, (double)w.y, a1);
                a2 = fma(x, (double)w.z, a2);
                a3 = fma(x, (double)w.w, a3);
            }
            part[cls][hp][q4p+0] = a0; part[cls][hp][q4p+1] = a1;
            part[cls][hp][q4p+2] = a2; part[cls][hp][q4p+3] = a3;
        }
        __syncthreads();
        if (r < 64) {
            zp2[cls][r] = ((part[cls][0][r] + part[cls][1][r])
                         + (part[cls][2][r] + part[cls][3][r]))
                        + ((part[cls][4][r] + part[cls][5][r])
                         + (part[cls][6][r] + part[cls][7][r]));
        }
        __syncthreads();

        // VQ argmin: thread t owns codes t, t+256; each crow f4 load feeds
        // BOTH classes' distance chains (R8's exact s0/s1 order).
        double bestA = 1e300, bestB = 1e300; int biA = 0, biB = 0;
        for (int k = t; k < VQN; k += 256) {
            const float* crow = cb + (size_t)k * 64;
            double sA0 = 0.0, sA1 = 0.0, sB0 = 0.0, sB1 = 0.0;
            #pragma unroll
            for (int j4 = 0; j4 < 16; ++j4) {
                f4 v = *(const f4*)(crow + (j4 << 2));
                int j = j4 << 2;
                double w0 = (double)v.x, w1 = (double)v.y;
                double w2 = (double)v.z, w3 = (double)v.w;
                double dA0 = zp2[0][j+0] - w0, dA1 = zp2[0][j+1] - w1;
                double dA2 = zp2[0][j+2] - w2, dA3 = zp2[0][j+3] - w3;
                double dB0 = zp2[1][j+0] - w0, dB1 = zp2[1][j+1] - w1;
                double dB2 = zp2[1][j+2] - w2, dB3 = zp2[1][j+3] - w3;
                sA0 = fma(dA0, dA0, sA0);  sA1 = fma(dA1, dA1, sA1);
                sA0 = fma(dA2, dA2, sA0);  sA1 = fma(dA3, dA3, sA1);
                sB0 = fma(dB0, dB0, sB0);  sB1 = fma(dB1, dB1, sB1);
                sB0 = fma(dB2, dB2, sB0);  sB1 = fma(dB3, dB3, sB1);
            }
            double sA = sA0 + sA1, sB = sB0 + sB1;
            if (sA < bestA) { bestA = sA; biA = k; }   // first-min, ascending
            if (sB < bestB) { bestB = sB; biB = k; }
        }
        // (min d, min idx) lattice within wave, then across 4 waves via LDS
        for (int off = 32; off > 0; off >>= 1) {
            double od = __shfl_down(bestA, off);
            int    oi = __shfl_down(biA, off);
            if (od < bestA || (od == bestA && oi < biA)) { bestA = od; biA = oi; }
            od = __shfl_down(bestB, off);
            oi = __shfl_down(biB, off);
            if (od < bestB || (od == bestB && oi < biB)) { bestB = od; biB = oi; }
        }
        {
            int wv = t >> 6;
            if ((t & 63) == 0) {
                rda[0][wv] = bestA; ria[0][wv] = biA;
                rda[1][wv] = bestB; ria[1][wv] = biB;
            }
        }
        __syncthreads();
        if (t < 2) {
            double b0 = rda[t][0]; int i0 = ria[t][0];
            for (int wv = 1; wv < 4; ++wv) {
                if (rda[t][wv] < b0 || (rda[t][wv] == b0 && ria[t][wv] < i0)) {
                    b0 = rda[t][wv]; i0 = ria[t][wv];
                }
            }
            widx2[t] = i0;
        }
        __syncthreads();
        const int widxA = widx2[0], widxB = widx2[1];
        if (t < 64)       qv2[0][t]      = cb[(size_t)widxA * 64 + t];
        else if (t < 128) qv2[1][t - 64] = cb[(size_t)widxB * 64 + (t - 64)];
        __syncthreads();

        if (t == 0) {
            idx_t[c0] = widxA;
            double e0 = 0.0, e1 = 0.0;
            for (int j = 0; j < 64; j += 2) {
                double d0 = (double)qv2[0][j]   - zp2[0][j];
                double d1 = (double)qv2[0][j+1] - zp2[0][j+1];
                e0 = fma(d0, d0, e0); e1 = fma(d1, d1, e1);
            }
            e_t[c0] = (float)(e0 + e1);
        }
        if (t == 128 && c1 != c0) {
            idx_t[c1] = widxB;
            double e0 = 0.0, e1 = 0.0;
            for (int j = 0; j < 64; j += 2) {
                double d0 = (double)qv2[1][j]   - zp2[1][j];
                double d1 = (double)qv2[1][j+1] - zp2[1][j+1];
                e0 = fma(d0, d0, e0); e1 = fma(d1, d1, e1);
            }
            e_t[c1] = (float)(e0 + e1);
        }
    } else {
        // ============ heads per CODE (2 codes/block, streaming loads) ============
        const int g  = t >> 7;                 // code slot 0/1
        const int tt = t & 127;
        int k = (bid - nTB) * 2 + g;
        const int kk = (k < VQN) ? k : VQN - 1;    // clamp (dup-safe)
        const int q4 = (tt & 31) << 2;

        if (tt < 64) qvh[g][tt] = cb[(size_t)kk * 64 + tt];
        __syncthreads();

        // H1: slots (tt>>5): 0=Wa-even, 1=Wa-odd, 2=Ws-even, 3=Ws-odd.
        // Accumulation sequence s=0..31 == R8's two 16-groups.
        {
            const int m  = tt >> 6;
            const int hh = (tt >> 5) & 1;
            const float* Wm = m ? Ws : Wa;
            const float* bm = m ? bs : ba;
            float a0 = hh ? 0.0f : bm[q4+0];
            float a1 = hh ? 0.0f : bm[q4+1];
            float a2 = hh ? 0.0f : bm[q4+2];
            float a3 = hh ? 0.0f : bm[q4+3];
            #pragma unroll
            for (int s = 0; s < 32; ++s) {
                f4 w = *(const f4*)(Wm + (size_t)(hh + (s << 1)) * 128 + q4);
                float qj = qvh[g][hh + (s << 1)];
                a0 = fmaf(qj, w.x, a0);
                a1 = fmaf(qj, w.y, a1);
                a2 = fmaf(qj, w.z, a2);
                a3 = fmaf(qj, w.w, a3);
            }
            fpart[g][tt >> 5][q4+0] = a0; fpart[g][tt >> 5][q4+1] = a1;
            fpart[g][tt >> 5][q4+2] = a2; fpart[g][tt >> 5][q4+3] = a3;
        }
        __syncthreads();

        // H2: tt<64 compute Wc1 chains; tt>=64 combine+store am/sd per code
        if (tt < 64) {
            const int hh = tt >> 5;
            float a0 = hh ? 0.0f : bc1[q4+0];
            float a1 = hh ? 0.0f : bc1[q4+1];
            float a2 = hh ? 0.0f : bc1[q4+2];
            float a3 = hh ? 0.0f : bc1[q4+3];
            #pragma unroll
            for (int s = 0; s < 32; ++s) {
                f4 w = *(const f4*)(Wc1 + (size_t)(hh + (s << 1)) * 128 + q4);
                float qj = qvh[g][hh + (s << 1)];
                a0 = fmaf(qj, w.x, a0);
                a1 = fmaf(qj, w.y, a1);
                a2 = fmaf(qj, w.z, a2);
                a3 = fmaf(qj, w.w, a3);
            }
            gpart[g][hh][q4+0] = a0; gpart[g][hh][q4+1] = a1;
            gpart[g][hh][q4+2] = a2; gpart[g][hh][q4+3] = a3;
        } else {
            int o = (tt - 64) << 1;
            am_c[(size_t)kk * 128 + o]     = sigmoidf_(fpart[g][0][o]   + fpart[g][1][o]);
            am_c[(size_t)kk * 128 + o + 1] = sigmoidf_(fpart[g][0][o+1] + fpart[g][1][o+1]);
            sd_c[(size_t)kk * 128 + o]     = sigmoidf_(fpart[g][2][o]   + fpart[g][3][o])   * 1.0f + 1e-8f;
            sd_c[(size_t)kk * 128 + o + 1] = sigmoidf_(fpart[g][2][o+1] + fpart[g][3][o+1]) * 1.0f + 1e-8f;
        }
        __syncthreads();
        h1s[g][tt] = sigmoidf_(gpart[g][0][tt] + gpart[g][1][tt]);
        __syncthreads();

        // critic layer 2 (128->128): s=0..63 sequential (== R8's 4x16)
        {
            const int o2 = (tt & 63) << 1;
            const int hh = tt >> 6;
            float a0 = hh ? 0.0f : bc2[o2+0];
            float a1 = hh ? 0.0f : bc2[o2+1];
            #pragma unroll
            for (int s = 0; s < 64; ++s) {
                f2 w = *(const f2*)(Wc2 + (size_t)(hh + (s << 1)) * 128 + o2);
                float x = h1s[g][hh + (s << 1)];
                a0 = fmaf(x, w.x, a0);
                a1 = fmaf(x, w.y, a1);
            }
            gpart[g][hh][o2+0] = a0; gpart[g][hh][o2+1] = a1;
        }
        __syncthreads();
        h2s[g][tt] = sigmoidf_(gpart[g][0][tt] + gpart[g][1][tt]);
        __syncthreads();

        // critic layer 3 (128->32): s=0..63 sequential, tt<32
        if (tt < 32) {
            const int o2 = (tt & 15) << 1;
            const int hh = tt >> 4;
            float a0 = hh ? 0.0f : bc3[o2+0];
            float a1 = hh ? 0.0f : bc3[o2+1];
            #pragma unroll
            for (int s = 0; s < 64; ++s) {
                f2 w = *(const f2*)(Wc3 + (size_t)(hh + (s << 1)) * 32 + o2);
                float x = h2s[g][hh + (s << 1)];
                a0 = fmaf(x, w.x, a0);
                a1 = fmaf(x, w.y, a1);
            }
            gpart[g][hh][o2+0] = a0; gpart[g][hh][o2+1] = a1;
        }
        __syncthreads();
        if (tt < 32) h3s[g][tt] = sigmoidf_(gpart[g][0][tt] + gpart[g][1][tt]);
        __syncthreads();

        if (tt == 0) {
            float l4 = bc4[0];
            for (int i = 0; i < 32; ++i) l4 = fmaf(h3s[g][i], Wc4[i], l4);
            cr_c[kk] = l4;             // no sigmoid on final critic layer
        }
    }
}

// Merged scatter: blocks [0, vecBlocks) emit BOTH am and sd float4 per
// thread from one obs read + one idx_t indirection (L1-hot, 4 KB);
// trailing blocks do the critic/idx scatter and vq_loss reduction.
__global__ __launch_bounds__(256) void scatter_kernel(
    const int* __restrict__ obs,
    const f4* __restrict__ am_c, const f4* __restrict__ sd_c,
    const float* __restrict__ cr_c, const int* __restrict__ idx_t,
    const float* __restrict__ e_t,
    f4* __restrict__ out_vec, float* __restrict__ out_critic,
    float* __restrict__ out_idx, float* __restrict__ out_loss,
    int B, float scale)
{
    __shared__ float red[256];
    const int vecBlocks = (B * 32) / 256;           // B*128/4 f4-slots per half
    if ((int)blockIdx.x < vecBlocks) {
        int gid = blockIdx.x * 256 + threadIdx.x;
        int b = gid >> 5;                           // 32 float4 per row
        int j = gid & 31;
        int k = idx_t[obs[b]];
        size_t row = (size_t)k * 32 + j;
        __builtin_nontemporal_store(am_c[row], &out_vec[gid]);
        __builtin_nontemporal_store(sd_c[row], &out_vec[(size_t)B * 32 + gid]);
        return;
    }
    int b = (blockIdx.x - vecBlocks) * 256 + threadIdx.x;
    float e = 0.0f;
    if (b < B) {
        int o = obs[b];
        int k = idx_t[o];
        __builtin_nontemporal_store(cr_c[k], &out_critic[b]);
        __builtin_nontemporal_store((float)k, &out_idx[b]);
        e = e_t[o];
    }
    red[threadIdx.x] = e;
    __syncthreads();
    for (int s = 128; s > 0; s >>= 1) {
        if (threadIdx.x < s) red[threadIdx.x] += red[threadIdx.x + s];
        __syncthreads();
    }
    if (threadIdx.x == 0) atomicAdd(out_loss, red[0] * scale);
}

extern "C" void kernel_launch(void* const* d_in, const int* in_sizes, int n_in,
                              void* d_out, int out_size, void* d_ws, size_t ws_size,
                              hipStream_t stream)
{
    const int*   obs   = (const int*)  d_in[0];
    const float* embed = (const float*)d_in[1];
    const float* W1    = (const float*)d_in[2];
    const float* b1    = (const float*)d_in[3];
    const float* W2    = (const float*)d_in[4];
    const float* b2    = (const float*)d_in[5];
    const float* W3    = (const float*)d_in[6];
    const float* b3    = (const float*)d_in[7];
    const float* Wp    = (const float*)d_in[8];
    const float* bp    = (const float*)d_in[9];
    const float* cb    = (const float*)d_in[10];
    const float* Wa    = (const float*)d_in[11];
    const float* ba    = (const float*)d_in[12];
    const float* Ws    = (const float*)d_in[13];
    const float* bs    = (const float*)d_in[14];
    const float* Wc1   = (const float*)d_in[15];
    const float* bc1   = (const float*)d_in[16];
    const float* Wc2   = (const float*)d_in[17];
    const float* bc2   = (const float*)d_in[18];
    const float* Wc3   = (const float*)d_in[19];
    const float* bc3   = (const float*)d_in[20];
    const float* Wc4   = (const float*)d_in[21];
    const float* bc4   = (const float*)d_in[22];

    const int B   = in_sizes[0];
    const int NC  = in_sizes[1] / 128;
    const int VQN = in_sizes[10] / 64;

    // workspace tables: per-code am/sd/cr + per-class idx/e (~530 KB)
    float* am_c = (float*)d_ws;
    float* sd_c = am_c + (size_t)VQN * 128;
    float* cr_c = sd_c + (size_t)VQN * 128;
    float* e_t  = cr_c + VQN;
    int*   idx_t = (int*)(e_t + NC);

    float* out = (float*)d_out;
    const size_t cr_off   = (size_t)B * 256;     // after am (B*128) + sd (B*128)
    const size_t loss_off = cr_off + (size_t)B;
    const size_t idx_off  = loss_off + 1;

    const int nTB = (NC + 1) / 2;                // trunk blocks (2 classes each)
    const int nHB = (VQN + 1) / 2;               // head blocks (2 codes each)

    compute_kernel<<<nTB + nHB, 256, 0, stream>>>(
        embed, W1, b1, W2, b2, W3, b3, Wp, bp, cb,
        Wa, ba, Ws, bs, Wc1, bc1, Wc2, bc2, Wc3, bc3, Wc4, bc4,
        am_c, sd_c, cr_c, idx_t, e_t, out + loss_off, VQN, NC, nTB);

    const int vecBlocks    = (B * 32) / 256;
    const int scalarBlocks = (B + 255) / 256;
    scatter_kernel<<<vecBlocks + scalarBlocks, 256, 0, stream>>>(
        obs, (const f4*)am_c, (const f4*)sd_c, cr_c, idx_t, e_t,
        (f4*)out, out + cr_off, out + idx_off, out + loss_off,
        B, 1.25f / ((float)B * 64.0f));
}

// Round 9
// 249.127 us; speedup vs baseline: 1.0603x; 1.0603x over previous
//
#include <hip/hip_runtime.h>
#include <math.h>

// Outputs are a pure function of obs's class (NC=1000); heads (am/sd/cr)
// are a pure function of the VQ CODE (VQN=512).
//
// R12: surviving bottleneck model = per-block WEIGHT RE-READ traffic
// (~330KB/trunk block, ~176KB/head block; R8/R9's ~210MB @ ~5TB/s eff ~=
// the observed 42-47us). Lever: amortize — 4 classes per trunk block
// (each f4 weight load feeds 4 fp64 chain sets) and 8 codes per head
// block (each 128-group computes 4 codes per weight load). Trunk traffic
// 165->82MB, heads 45->11MB, blocks 756->314. Per-class/per-code chain
// content, order, tie-breaks verbatim R8 => absmax 0. No launch_bounds
// cap (R11: capping below natural VGPR footprint spills).

typedef float f4 __attribute__((ext_vector_type(4)));
typedef float f2 __attribute__((ext_vector_type(2)));

__device__ __forceinline__ float sigmoidf_(float x){ return 1.0f/(1.0f + expf(-x)); }

__global__ __launch_bounds__(256) void compute_kernel(
    const float* __restrict__ embed,
    const float* __restrict__ W1, const float* __restrict__ b1,
    const float* __restrict__ W2, const float* __restrict__ b2,
    const float* __restrict__ W3, const float* __restrict__ b3,
    const float* __restrict__ Wp, const float* __restrict__ bp,
    const float* __restrict__ cb,
    const float* __restrict__ Wa, const float* __restrict__ ba,
    const float* __restrict__ Ws, const float* __restrict__ bs,
    const float* __restrict__ Wc1, const float* __restrict__ bc1,
    const float* __restrict__ Wc2, const float* __restrict__ bc2,
    const float* __restrict__ Wc3, const float* __restrict__ bc3,
    const float* __restrict__ Wc4, const float* __restrict__ bc4,
    float* __restrict__ am_c, float* __restrict__ sd_c,
    float* __restrict__ cr_c, int* __restrict__ idx_t, float* __restrict__ e_t,
    float* __restrict__ loss_slot, int VQN, int NC, int nTB)
{
    const int bid = blockIdx.x;
    const int t   = threadIdx.x;     // 0..255
    if (bid == 0 && t == 0) *loss_slot = 0.0f;   // d_out is poisoned each call

    // trunk-branch LDS (4 classes)
    __shared__ double U[4][128], V[4][128];     // layer ping-pong per class
    __shared__ double part[4][8][128];          // fp64 chain partials
    __shared__ double zp4[4][64];
    __shared__ float  qv4[4][64];
    __shared__ double rda[4][4];
    __shared__ int    ria[4][4];
    __shared__ int    widx4[4];
    // head-branch LDS (2 groups x 4 codes)
    __shared__ float  qvh[8][64];
    __shared__ float  fpart[2][4][4][128];
    __shared__ float  gpart[2][4][2][128];
    __shared__ float  h1s[2][4][128], h2s[2][4][128], h3s[2][4][32];

    if (bid < nTB) {
        // ================= trunk + VQ for classes c0..c3 =================
        const int cbase = bid * 4;
        int cidx[4];
        #pragma unroll
        for (int cd = 0; cd < 4; ++cd) {
            int c = cbase + cd;
            cidx[cd] = (c < NC) ? c : NC - 1;    // clamp (dup-safe)
        }
        const int q4  = (t & 31) << 2;   // output quad (shared-load phases)
        const int h   = t >> 5;          // K-chain 0..7 (i ≡ h mod 8)
        const int cw  = t >> 6;          // this thread's class for combines
        const int r2  = t & 63;          // combine sub-index

        // y = embed[c]: 4x128 loads, 2 per thread
        U[cw][r2]      = (double)embed[(size_t)cidx[cw] * 128 + r2];
        U[cw][r2 + 64] = (double)embed[(size_t)cidx[cw] * 128 + r2 + 64];
        __syncthreads();

        // trunk layer: thread (h,q4) computes chain h of outputs q4..q4+3
        // for ALL 4 classes from one f4 weight load. Chain 0 carries bias.
        // Per-class chain order verbatim R8.
#define TRUNK4(Wm, bv, IN, OUT)                                               \
        {                                                                     \
            double i0 = (h == 0) ? (double)bv[q4+0] : 0.0;                    \
            double i1 = (h == 0) ? (double)bv[q4+1] : 0.0;                    \
            double i2 = (h == 0) ? (double)bv[q4+2] : 0.0;                    \
            double i3 = (h == 0) ? (double)bv[q4+3] : 0.0;                    \
            double a0[4], a1[4], a2[4], a3[4];                                \
            _Pragma("unroll")                                                 \
            for (int cd = 0; cd < 4; ++cd) {                                  \
                a0[cd] = i0; a1[cd] = i1; a2[cd] = i2; a3[cd] = i3;           \
            }                                                                 \
            _Pragma("unroll")                                                 \
            for (int s = 0; s < 16; ++s) {                                    \
                int i = h + (s << 3);                                         \
                f4 w = *(const f4*)(Wm + (size_t)i * 128 + q4);               \
                double w0 = (double)w.x, w1 = (double)w.y;                    \
                double w2 = (double)w.z, w3 = (double)w.w;                    \
                _Pragma("unroll")                                             \
                for (int cd = 0; cd < 4; ++cd) {                              \
                    double x = IN[cd][i];                                     \
                    a0[cd] = fma(x, w0, a0[cd]);                              \
                    a1[cd] = fma(x, w1, a1[cd]);                              \
                    a2[cd] = fma(x, w2, a2[cd]);                              \
                    a3[cd] = fma(x, w3, a3[cd]);                              \
                }                                                             \
            }                                                                 \
            _Pragma("unroll")                                                 \
            for (int cd = 0; cd < 4; ++cd) {                                  \
                part[cd][h][q4+0] = a0[cd]; part[cd][h][q4+1] = a1[cd];       \
                part[cd][h][q4+2] = a2[cd]; part[cd][h][q4+3] = a3[cd];       \
            }                                                                 \
        }                                                                     \
        __syncthreads();                                                      \
        {                                                                     \
            _Pragma("unroll")                                                 \
            for (int u = 0; u < 2; ++u) {                                     \
                int rr = r2 + (u << 6);                                       \
                double acc = ((part[cw][0][rr] + part[cw][1][rr])             \
                            + (part[cw][2][rr] + part[cw][3][rr]))            \
                           + ((part[cw][4][rr] + part[cw][5][rr])             \
                            + (part[cw][6][rr] + part[cw][7][rr]));           \
                OUT[cw][rr] = acc > 0.0 ? acc : 0.0;                          \
            }                                                                 \
        }                                                                     \
        __syncthreads();

        TRUNK4(W1, b1, U, V)
        TRUNK4(W2, b2, V, U)
        TRUNK4(W3, b3, U, V)
#undef TRUNK4

        // zp = z3 @ Wp + bp (64 outs/class): per class 8 chains x 16 quads;
        // thread does chains hp and hp+4 of its class (same chain content).
        {
            const int q4p = (r2 & 15) << 2;
            const int hp0 = r2 >> 4;         // 0..3
            #pragma unroll
            for (int u = 0; u < 2; ++u) {
                const int hp = hp0 + (u << 2);   // 0..3 then 4..7
                double a0 = (hp == 0) ? (double)bp[q4p+0] : 0.0;
                double a1 = (hp == 0) ? (double)bp[q4p+1] : 0.0;
                double a2 = (hp == 0) ? (double)bp[q4p+2] : 0.0;
                double a3 = (hp == 0) ? (double)bp[q4p+3] : 0.0;
                #pragma unroll
                for (int s = 0; s < 16; ++s) {
                    int i = hp + (s << 3);
                    f4 w = *(const f4*)(Wp + (size_t)i * 64 + q4p);
                    double x = V[cw][i];
                    a0 = fma(x, (double)w.x, a0);
                    a1 = fma(x, (double)w.y, a1);
                    a2 = fma(x, (double)w.z, a2);
                    a3 = fma(x, (double)w.w, a3);
                }
                part[cw][hp][q4p+0] = a0; part[cw][hp][q4p+1] = a1;
                part[cw][hp][q4p+2] = a2; part[cw][hp][q4p+3] = a3;
            }
        }
        __syncthreads();
        zp4[cw][r2] = ((part[cw][0][r2] + part[cw][1][r2])
                     + (part[cw][2][r2] + part[cw][3][r2]))
                    + ((part[cw][4][r2] + part[cw][5][r2])
                     + (part[cw][6][r2] + part[cw][7][r2]));
        __syncthreads();

        // VQ argmin: thread t owns codes t, t+256; each crow f4 load feeds
        // ALL 4 classes' distance chains (R8's exact s0/s1 order per class).
        double best[4]; int bi[4];
        #pragma unroll
        for (int cd = 0; cd < 4; ++cd) { best[cd] = 1e300; bi[cd] = 0; }
        for (int k = t; k < VQN; k += 256) {
            const float* crow = cb + (size_t)k * 64;
            double s0[4], s1[4];
            #pragma unroll
            for (int cd = 0; cd < 4; ++cd) { s0[cd] = 0.0; s1[cd] = 0.0; }
            #pragma unroll
            for (int j4 = 0; j4 < 16; ++j4) {
                f4 v = *(const f4*)(crow + (j4 << 2));
                int j = j4 << 2;
                double w0 = (double)v.x, w1 = (double)v.y;
                double w2 = (double)v.z, w3 = (double)v.w;
                #pragma unroll
                for (int cd = 0; cd < 4; ++cd) {
                    double d0 = zp4[cd][j+0] - w0, d1 = zp4[cd][j+1] - w1;
                    double d2 = zp4[cd][j+2] - w2, d3 = zp4[cd][j+3] - w3;
                    s0[cd] = fma(d0, d0, s0[cd]);  s1[cd] = fma(d1, d1, s1[cd]);
                    s0[cd] = fma(d2, d2, s0[cd]);  s1[cd] = fma(d3, d3, s1[cd]);
                }
            }
            #pragma unroll
            for (int cd = 0; cd < 4; ++cd) {
                double s = s0[cd] + s1[cd];
                if (s < best[cd]) { best[cd] = s; bi[cd] = k; }  // first-min, ascending
            }
        }
        // (min d, min idx) lattice within wave, then across 4 waves via LDS
        for (int off = 32; off > 0; off >>= 1) {
            #pragma unroll
            for (int cd = 0; cd < 4; ++cd) {
                double od = __shfl_down(best[cd], off);
                int    oi = __shfl_down(bi[cd], off);
                if (od < best[cd] || (od == best[cd] && oi < bi[cd])) {
                    best[cd] = od; bi[cd] = oi;
                }
            }
        }
        {
            int wv = t >> 6;
            if ((t & 63) == 0) {
                #pragma unroll
                for (int cd = 0; cd < 4; ++cd) { rda[cd][wv] = best[cd]; ria[cd][wv] = bi[cd]; }
            }
        }
        __syncthreads();
        if (t < 4) {
            double b0 = rda[t][0]; int i0 = ria[t][0];
            for (int wv = 1; wv < 4; ++wv) {
                if (rda[t][wv] < b0 || (rda[t][wv] == b0 && ria[t][wv] < i0)) {
                    b0 = rda[t][wv]; i0 = ria[t][wv];
                }
            }
            widx4[t] = i0;
        }
        __syncthreads();
        qv4[cw][r2] = cb[(size_t)widx4[cw] * 64 + r2];
        __syncthreads();

        // per-class epilogue: threads 0,64,128,192 handle classes 0..3
        if (r2 == 0) {
            const int cd = cw;
            int c = cbase + cd;
            if (c < NC || cd == 0) {
                const int cc = cidx[cd];
                idx_t[cc] = widx4[cd];
                double e0 = 0.0, e1 = 0.0;
                for (int j = 0; j < 64; j += 2) {
                    double d0 = (double)qv4[cd][j]   - zp4[cd][j];
                    double d1 = (double)qv4[cd][j+1] - zp4[cd][j+1];
                    e0 = fma(d0, d0, e0); e1 = fma(d1, d1, e1);
                }
                e_t[cc] = (float)(e0 + e1);
            }
        }
    } else {
        // ===== heads per CODE: 8 codes/block = 2 groups x 4 codes; each
        // weight load feeds 4 codes' chains (per-code order verbatim R8) =====
        const int gg = t >> 7;                 // group 0/1
        const int tt = t & 127;
        const int kbase = (bid - nTB) * 8 + gg * 4;
        int kk[4];
        #pragma unroll
        for (int cd = 0; cd < 4; ++cd) {
            int k = kbase + cd;
            kk[cd] = (k < VQN) ? k : VQN - 1;      // clamp (dup-safe)
        }
        const int q4 = (tt & 31) << 2;

        // qvh: 4 codes x 64 dims per group; thread does dims (tt&31), +32
        {
            const int cd = tt >> 5;
            const int dm = tt & 31;
            qvh[gg * 4 + cd][dm]      = cb[(size_t)kk[cd] * 64 + dm];
            qvh[gg * 4 + cd][dm + 32] = cb[(size_t)kk[cd] * 64 + dm + 32];
        }
        __syncthreads();

        // H1: slots (tt>>5): 0=Wa-even, 1=Wa-odd, 2=Ws-even, 3=Ws-odd.
        // s=0..31 sequential per code == R8.
        {
            const int m  = tt >> 6;
            const int hh = (tt >> 5) & 1;
            const float* Wm = m ? Ws : Wa;
            const float* bm = m ? bs : ba;
            float i0 = hh ? 0.0f : bm[q4+0];
            float i1 = hh ? 0.0f : bm[q4+1];
            float i2 = hh ? 0.0f : bm[q4+2];
            float i3 = hh ? 0.0f : bm[q4+3];
            float a0[4], a1[4], a2[4], a3[4];
            #pragma unroll
            for (int cd = 0; cd < 4; ++cd) { a0[cd]=i0; a1[cd]=i1; a2[cd]=i2; a3[cd]=i3; }
            #pragma unroll
            for (int s = 0; s < 32; ++s) {
                f4 w = *(const f4*)(Wm + (size_t)(hh + (s << 1)) * 128 + q4);
                #pragma unroll
                for (int cd = 0; cd < 4; ++cd) {
                    float qj = qvh[gg * 4 + cd][hh + (s << 1)];
                    a0[cd] = fmaf(qj, w.x, a0[cd]);
                    a1[cd] = fmaf(qj, w.y, a1[cd]);
                    a2[cd] = fmaf(qj, w.z, a2[cd]);
                    a3[cd] = fmaf(qj, w.w, a3[cd]);
                }
            }
            #pragma unroll
            for (int cd = 0; cd < 4; ++cd) {
                fpart[gg][cd][tt >> 5][q4+0] = a0[cd];
                fpart[gg][cd][tt >> 5][q4+1] = a1[cd];
                fpart[gg][cd][tt >> 5][q4+2] = a2[cd];
                fpart[gg][cd][tt >> 5][q4+3] = a3[cd];
            }
        }
        __syncthreads();

        // H2: tt<64 compute Wc1 chains (shared across codes); tt>=64 store am/sd
        if (tt < 64) {
            const int hh = tt >> 5;
            float i0 = hh ? 0.0f : bc1[q4+0];
            float i1 = hh ? 0.0f : bc1[q4+1];
            float i2 = hh ? 0.0f : bc1[q4+2];
            float i3 = hh ? 0.0f : bc1[q4+3];
            float a0[4], a1[4], a2[4], a3[4];
            #pragma unroll
            for (int cd = 0; cd < 4; ++cd) { a0[cd]=i0; a1[cd]=i1; a2[cd]=i2; a3[cd]=i3; }
            #pragma unroll
            for (int s = 0; s < 32; ++s) {
                f4 w = *(const f4*)(Wc1 + (size_t)(hh + (s << 1)) * 128 + q4);
                #pragma unroll
                for (int cd = 0; cd < 4; ++cd) {
                    float qj = qvh[gg * 4 + cd][hh + (s << 1)];
                    a0[cd] = fmaf(qj, w.x, a0[cd]);
                    a1[cd] = fmaf(qj, w.y, a1[cd]);
                    a2[cd] = fmaf(qj, w.z, a2[cd]);
                    a3[cd] = fmaf(qj, w.w, a3[cd]);
                }
            }
            #pragma unroll
            for (int cd = 0; cd < 4; ++cd) {
                gpart[gg][cd][hh][q4+0] = a0[cd];
                gpart[gg][cd][hh][q4+1] = a1[cd];
                gpart[gg][cd][hh][q4+2] = a2[cd];
                gpart[gg][cd][hh][q4+3] = a3[cd];
            }
        } else {
            int o = (tt - 64) << 1;
            #pragma unroll
            for (int cd = 0; cd < 4; ++cd) {
                size_t base = (size_t)kk[cd] * 128;
                am_c[base + o]     = sigmoidf_(fpart[gg][cd][0][o]   + fpart[gg][cd][1][o]);
                am_c[base + o + 1] = sigmoidf_(fpart[gg][cd][0][o+1] + fpart[gg][cd][1][o+1]);
                sd_c[base + o]     = sigmoidf_(fpart[gg][cd][2][o]   + fpart[gg][cd][3][o])   * 1.0f + 1e-8f;
                sd_c[base + o + 1] = sigmoidf_(fpart[gg][cd][2][o+1] + fpart[gg][cd][3][o+1]) * 1.0f + 1e-8f;
            }
        }
        __syncthreads();
        #pragma unroll
        for (int cd = 0; cd < 4; ++cd)
            h1s[gg][cd][tt] = sigmoidf_(gpart[gg][cd][0][tt] + gpart[gg][cd][1][tt]);
        __syncthreads();

        // critic layer 2 (128->128): s=0..63 sequential, shared f2 loads
        {
            const int o2 = (tt & 63) << 1;
            const int hh = tt >> 6;
            float i0 = hh ? 0.0f : bc2[o2+0];
            float i1 = hh ? 0.0f : bc2[o2+1];
            float a0[4], a1[4];
            #pragma unroll
            for (int cd = 0; cd < 4; ++cd) { a0[cd] = i0; a1[cd] = i1; }
            #pragma unroll
            for (int s = 0; s < 64; ++s) {
                f2 w = *(const f2*)(Wc2 + (size_t)(hh + (s << 1)) * 128 + o2);
                #pragma unroll
                for (int cd = 0; cd < 4; ++cd) {
                    float x = h1s[gg][cd][hh + (s << 1)];
                    a0[cd] = fmaf(x, w.x, a0[cd]);
                    a1[cd] = fmaf(x, w.y, a1[cd]);
                }
            }
            #pragma unroll
            for (int cd = 0; cd < 4; ++cd) {
                gpart[gg][cd][hh][o2+0] = a0[cd];
                gpart[gg][cd][hh][o2+1] = a1[cd];
            }
        }
        __syncthreads();
        #pragma unroll
        for (int cd = 0; cd < 4; ++cd)
            h2s[gg][cd][tt] = sigmoidf_(gpart[gg][cd][0][tt] + gpart[gg][cd][1][tt]);
        __syncthreads();

        // critic layer 3 (128->32): s=0..63 sequential, tt<32
        if (tt < 32) {
            const int o2 = (tt & 15) << 1;
            const int hh = tt >> 4;
            float i0 = hh ? 0.0f : bc3[o2+0];
            float i1 = hh ? 0.0f : bc3[o2+1];
            float a0[4], a1[4];
            #pragma unroll
            for (int cd = 0; cd < 4; ++cd) { a0[cd] = i0; a1[cd] = i1; }
            #pragma unroll
            for (int s = 0; s < 64; ++s) {
                f2 w = *(const f2*)(Wc3 + (size_t)(hh + (s << 1)) * 32 + o2);
                #pragma unroll
                for (int cd = 0; cd < 4; ++cd) {
                    float x = h2s[gg][cd][hh + (s << 1)];
                    a0[cd] = fmaf(x, w.x, a0[cd]);
                    a1[cd] = fmaf(x, w.y, a1[cd]);
                }
            }
            #pragma unroll
            for (int cd = 0; cd < 4; ++cd) {
                gpart[gg][cd][hh][o2+0] = a0[cd];
                gpart[gg][cd][hh][o2+1] = a1[cd];
            }
        }
        __syncthreads();
        if (tt < 32) {
            #pragma unroll
            for (int cd = 0; cd < 4; ++cd)
                h3s[gg][cd][tt] = sigmoidf_(gpart[gg][cd][0][tt] + gpart[gg][cd][1][tt]);
        }
        __syncthreads();

        // cr: threads 0..3 of each group handle one code each (order == R8)
        if (tt < 4) {
            const int cd = tt;
            float l4 = bc4[0];
            for (int i = 0; i < 32; ++i) l4 = fmaf(h3s[gg][cd][i], Wc4[i], l4);
            cr_c[kk[cd]] = l4;         // no sigmoid on final critic layer
        }
    }
}

// Merged scatter: blocks [0, vecBlocks) emit BOTH am and sd float4 per
// thread from one obs read + one idx_t indirection (L1-hot, 4 KB);
// trailing blocks do the critic/idx scatter and vq_loss reduction.
__global__ __launch_bounds__(256) void scatter_kernel(
    const int* __restrict__ obs,
    const f4* __restrict__ am_c, const f4* __restrict__ sd_c,
    const float* __restrict__ cr_c, const int* __restrict__ idx_t,
    const float* __restrict__ e_t,
    f4* __restrict__ out_vec, float* __restrict__ out_critic,
    float* __restrict__ out_idx, float* __restrict__ out_loss,
    int B, float scale)
{
    __shared__ float red[256];
    const int vecBlocks = (B * 32) / 256;           // B*128/4 f4-slots per half
    if ((int)blockIdx.x < vecBlocks) {
        int gid = blockIdx.x * 256 + threadIdx.x;
        int b = gid >> 5;                           // 32 float4 per row
        int j = gid & 31;
        int k = idx_t[obs[b]];
        size_t row = (size_t)k * 32 + j;
        __builtin_nontemporal_store(am_c[row], &out_vec[gid]);
        __builtin_nontemporal_store(sd_c[row], &out_vec[(size_t)B * 32 + gid]);
        return;
    }
    int b = (blockIdx.x - vecBlocks) * 256 + threadIdx.x;
    float e = 0.0f;
    if (b < B) {
        int o = obs[b];
        int k = idx_t[o];
        __builtin_nontemporal_store(cr_c[k], &out_critic[b]);
        __builtin_nontemporal_store((float)k, &out_idx[b]);
        e = e_t[o];
    }
    red[threadIdx.x] = e;
    __syncthreads();
    for (int s = 128; s > 0; s >>= 1) {
        if (threadIdx.x < s) red[threadIdx.x] += red[threadIdx.x + s];
        __syncthreads();
    }
    if (threadIdx.x == 0) atomicAdd(out_loss, red[0] * scale);
}

extern "C" void kernel_launch(void* const* d_in, const int* in_sizes, int n_in,
                              void* d_out, int out_size, void* d_ws, size_t ws_size,
                              hipStream_t stream)
{
    const int*   obs   = (const int*)  d_in[0];
    const float* embed = (const float*)d_in[1];
    const float* W1    = (const float*)d_in[2];
    const float* b1    = (const float*)d_in[3];
    const float* W2    = (const float*)d_in[4];
    const float* b2    = (const float*)d_in[5];
    const float* W3    = (const float*)d_in[6];
    const float* b3    = (const float*)d_in[7];
    const float* Wp    = (const float*)d_in[8];
    const float* bp    = (const float*)d_in[9];
    const float* cb    = (const float*)d_in[10];
    const float* Wa    = (const float*)d_in[11];
    const float* ba    = (const float*)d_in[12];
    const float* Ws    = (const float*)d_in[13];
    const float* bs    = (const float*)d_in[14];
    const float* Wc1   = (const float*)d_in[15];
    const float* bc1   = (const float*)d_in[16];
    const float* Wc2   = (const float*)d_in[17];
    const float* bc2   = (const float*)d_in[18];
    const float* Wc3   = (const float*)d_in[19];
    const float* bc3   = (const float*)d_in[20];
    const float* Wc4   = (const float*)d_in[21];
    const float* bc4   = (const float*)d_in[22];

    const int B   = in_sizes[0];
    const int NC  = in_sizes[1] / 128;
    const int VQN = in_sizes[10] / 64;

    // workspace tables: per-code am/sd/cr + per-class idx/e (~530 KB)
    float* am_c = (float*)d_ws;
    float* sd_c = am_c + (size_t)VQN * 128;
    float* cr_c = sd_c + (size_t)VQN * 128;
    float* e_t  = cr_c + VQN;
    int*   idx_t = (int*)(e_t + NC);

    float* out = (float*)d_out;
    const size_t cr_off   = (size_t)B * 256;     // after am (B*128) + sd (B*128)
    const size_t loss_off = cr_off + (size_t)B;
    const size_t idx_off  = loss_off + 1;

    const int nTB = (NC + 3) / 4;                // trunk blocks (4 classes each)
    const int nHB = (VQN + 7) / 8;               // head blocks (8 codes each)

    compute_kernel<<<nTB + nHB, 256, 0, stream>>>(
        embed, W1, b1, W2, b2, W3, b3, Wp, bp, cb,
        Wa, ba, Ws, bs, Wc1, bc1, Wc2, bc2, Wc3, bc3, Wc4, bc4,
        am_c, sd_c, cr_c, idx_t, e_t, out + loss_off, VQN, NC, nTB);

    const int vecBlocks    = (B * 32) / 256;
    const int scalarBlocks = (B + 255) / 256;
    scatter_kernel<<<vecBlocks + scalarBlocks, 256, 0, stream>>>(
        obs, (const f4*)am_c, (const f4*)sd_c, cr_c, idx_t, e_t,
        (f4*)out, out + cr_off, out + idx_off, out + loss_off,
        B, 1.25f / ((float)B * 64.0f));
}